// Round 1
// baseline (901.213 us; speedup 1.0000x reference)
//
#include <hip/hip_runtime.h>
#include <float.h>

#define N_SEQ 2561      // 10*16*16 + 1
#define NPAD  2624      // 41 * 64
#define DIMD  1024
#define NHEAD 16
#define DHEAD 64

// ---------------- analytic mask ----------------
// attend(i,j) == true  <=>  reference mask_block[i][j] == False (participates)
__device__ __forceinline__ bool attend_ij(int i, int j) {
  if (i == 0) return j == 0;
  if (j == 0 || i > 2560 || j > 2560) return false;
  int qi = (i == 2560) ? 0 : i;   // i % 2560 for i in [1,2560]
  int kj = j - 1;
  int t  = qi >> 8, tk = kj >> 8;          // frame = 256
  if (tk > t || tk < t - 3) return false;  // te = 3, causal
  int r  = (qi >> 4) & 15, c  = qi & 15;
  int rk = (kj >> 4) & 15, ck = kj & 15;
  int dr = rk - r, dc = ck - c;
  if (dr < -2 || dr > 2 || dc < -2 || dc > 2) return false;  // 5x5 window
  return (tk < t) || (dr < 0) || (dr == 0 && dc < 0);        // raster-causal in-frame
}

// conservative liveness of a 64x64 (q-tile, k-tile) block
__device__ __forceinline__ bool tile_live(int i0, int j0) {
  int qlo = max(i0, 1), qhi = min(i0 + 63, 2559);
  if (qlo > qhi) return false;             // tile 40: only wrap row 2560 (fixed later)
  int klo = max(j0 - 1, 0), khi = min(j0 + 62, 2559);
  int tq0 = qlo >> 8, tq1 = qhi >> 8;
  int tk0 = klo >> 8, tk1 = khi >> 8;
  if (tk0 > tq1 || tk1 < tq0 - 3) return false;
  int rq0 = 0, rq1 = 15;
  if (tq0 == tq1) { rq0 = (qlo >> 4) & 15; rq1 = (qhi >> 4) & 15; }
  int rk0 = 0, rk1 = 15;
  if (tk0 == tk1) { rk0 = (klo >> 4) & 15; rk1 = (khi >> 4) & 15; }
  if (rk0 > rq1 + 2 || rk1 < rq0 - 2) return false;
  return true;
}

// ---------------- fp32 tiled GEMM: C[r][c] = scale * sum_k A[r][k]*B[k][c] (+bias) ----------------
// A: [*][1024] row-major (rows >= a_valid read as 0), B: [1024][1024], C: [*][1024]
__global__ __launch_bounds__(256) void gemm64(const float* __restrict__ A,
                                              const float* __restrict__ B,
                                              float* __restrict__ C,
                                              int a_valid, int c_write,
                                              float scale,
                                              const float* __restrict__ bias) {
  __shared__ float As[16][68];   // transposed: As[kk][row]
  __shared__ float Bs[16][68];
  const int i0 = blockIdx.y * 64;
  const int c0 = blockIdx.x * 64;
  const int t  = threadIdx.x;
  const int tx = t & 15, ty = t >> 4;
  const int arow = t >> 2, aseg = t & 3;   // A tile loader: 64 rows x 16 k
  const int brow = t >> 4, bseg = t & 15;  // B tile loader: 16 k x 64 cols
  float acc[4][4] = {};

  for (int k0 = 0; k0 < 1024; k0 += 16) {
    float4 av = make_float4(0.f, 0.f, 0.f, 0.f);
    if (i0 + arow < a_valid)
      av = *(const float4*)&A[(size_t)(i0 + arow) * DIMD + k0 + aseg * 4];
    float4 bv = *(const float4*)&B[(size_t)(k0 + brow) * DIMD + c0 + bseg * 4];
    __syncthreads();
    As[aseg * 4 + 0][arow] = av.x;
    As[aseg * 4 + 1][arow] = av.y;
    As[aseg * 4 + 2][arow] = av.z;
    As[aseg * 4 + 3][arow] = av.w;
    *(float4*)&Bs[brow][bseg * 4] = bv;
    __syncthreads();
#pragma unroll
    for (int kk = 0; kk < 16; ++kk) {
      float4 a = *(const float4*)&As[kk][ty * 4];
      float4 b = *(const float4*)&Bs[kk][tx * 4];
      acc[0][0] += a.x * b.x; acc[0][1] += a.x * b.y; acc[0][2] += a.x * b.z; acc[0][3] += a.x * b.w;
      acc[1][0] += a.y * b.x; acc[1][1] += a.y * b.y; acc[1][2] += a.y * b.z; acc[1][3] += a.y * b.w;
      acc[2][0] += a.z * b.x; acc[2][1] += a.z * b.y; acc[2][2] += a.z * b.z; acc[2][3] += a.z * b.w;
      acc[3][0] += a.w * b.x; acc[3][1] += a.w * b.y; acc[3][2] += a.w * b.z; acc[3][3] += a.w * b.w;
    }
  }
  const int cc = c0 + tx * 4;
  float b0 = 0.f, b1 = 0.f, b2 = 0.f, b3 = 0.f;
  if (bias) { b0 = bias[cc]; b1 = bias[cc + 1]; b2 = bias[cc + 2]; b3 = bias[cc + 3]; }
#pragma unroll
  for (int ii = 0; ii < 4; ++ii) {
    int r = i0 + ty * 4 + ii;
    if (r < c_write) {
      float4 o;
      o.x = acc[ii][0] * scale + b0;
      o.y = acc[ii][1] * scale + b1;
      o.z = acc[ii][2] * scale + b2;
      o.w = acc[ii][3] * scale + b3;
      *(float4*)&C[(size_t)r * DIMD + cc] = o;
    }
  }
}

// ---------------- flash attention, fp32, analytic mask ----------------
// Q/K/V: [NPAD][1024] row-major, head h occupies cols h*64..h*64+63. O same layout.
__global__ __launch_bounds__(256) void attn64(const float* __restrict__ Q,
                                              const float* __restrict__ K,
                                              const float* __restrict__ V,
                                              float* __restrict__ O) {
  const int i0 = blockIdx.x * 64;
  const int h  = blockIdx.y;
  const int t  = threadIdx.x;
  const int row = t >> 2, q4 = t & 3;     // thread owns (q-row=row, d-cols q4*16..+15, keys q4*16..+15)
  __shared__ float Ks[64][68];
  __shared__ float Vs[64][68];
  __shared__ float Ps[64][68];

  // Q row into registers (64 floats = 16 float4); padded rows are zeros in ws
  float4 qreg[16];
  {
    const float* qp = &Q[(size_t)(i0 + row) * DIMD + h * DHEAD];
#pragma unroll
    for (int u = 0; u < 16; ++u) qreg[u] = *(const float4*)&qp[u * 4];
  }

  const int gi = i0 + row;
  float m = -FLT_MAX, l = 0.f;
  float acc[16] = {};

  const int krow = t >> 2, kseg = t & 3;

  for (int jt = 0; jt < 41; ++jt) {
    const int j0 = jt * 64;
    if (!tile_live(i0, j0)) continue;

    __syncthreads();  // prior PV reads of Ks/Vs/Ps done
    {
      const float* kp = &K[(size_t)(j0 + krow) * DIMD + h * DHEAD + kseg * 16];
      const float* vp = &V[(size_t)(j0 + krow) * DIMD + h * DHEAD + kseg * 16];
#pragma unroll
      for (int u = 0; u < 4; ++u) {
        *(float4*)&Ks[krow][kseg * 16 + u * 4] = *(const float4*)&kp[u * 4];
        *(float4*)&Vs[krow][kseg * 16 + u * 4] = *(const float4*)&vp[u * 4];
      }
    }
    __syncthreads();

    // scores for keys j = q4*16 + jj
    float p[16];
    float smax = -FLT_MAX;
#pragma unroll
    for (int jj = 0; jj < 16; ++jj) {
      const int j = q4 * 16 + jj;
      float4 a4 = make_float4(0.f, 0.f, 0.f, 0.f);
#pragma unroll
      for (int d4 = 0; d4 < 16; ++d4) {
        float4 kv = *(const float4*)&Ks[j][d4 * 4];
        a4.x += qreg[d4].x * kv.x;
        a4.y += qreg[d4].y * kv.y;
        a4.z += qreg[d4].z * kv.z;
        a4.w += qreg[d4].w * kv.w;
      }
      float s = (a4.x + a4.y) + (a4.z + a4.w);
      s = attend_ij(gi, j0 + j) ? s : -FLT_MAX;
      p[jj] = s;
      smax = fmaxf(smax, s);
    }
    // row max across the 4 sibling lanes
    smax = fmaxf(smax, __shfl_xor(smax, 1));
    smax = fmaxf(smax, __shfl_xor(smax, 2));

    const float mnew = fmaxf(m, smax);
    const float f = __expf(m - mnew);   // 1 if both -FLT_MAX, 0 if m=-FLT_MAX<mnew
    float psum = 0.f;
#pragma unroll
    for (int jj = 0; jj < 16; ++jj) {
      float pv = __expf(p[jj] - mnew);  // masked: underflow to exactly 0 (or 1 if row fully masked)
      p[jj] = pv;
      psum += pv;
    }
    psum += __shfl_xor(psum, 1);
    psum += __shfl_xor(psum, 2);
    l = l * f + psum;
    m = mnew;
#pragma unroll
    for (int dd = 0; dd < 16; ++dd) acc[dd] *= f;
#pragma unroll
    for (int jj = 0; jj < 16; ++jj) Ps[row][q4 * 16 + jj] = p[jj];
    __syncthreads();

    // PV: acc[dd] += sum_j Ps[row][j] * Vs[j][q4*16+dd]
#pragma unroll
    for (int j4 = 0; j4 < 16; ++j4) {
      float4 pr = *(const float4*)&Ps[row][j4 * 4];
#pragma unroll
      for (int u = 0; u < 4; ++u) {
        const float pj = (u == 0) ? pr.x : (u == 1) ? pr.y : (u == 2) ? pr.z : pr.w;
        const float* vp = &Vs[j4 * 4 + u][q4 * 16];
        float4 v0 = *(const float4*)&vp[0];
        float4 v1 = *(const float4*)&vp[4];
        float4 v2 = *(const float4*)&vp[8];
        float4 v3 = *(const float4*)&vp[12];
        acc[0]  += pj * v0.x; acc[1]  += pj * v0.y; acc[2]  += pj * v0.z; acc[3]  += pj * v0.w;
        acc[4]  += pj * v1.x; acc[5]  += pj * v1.y; acc[6]  += pj * v1.z; acc[7]  += pj * v1.w;
        acc[8]  += pj * v2.x; acc[9]  += pj * v2.y; acc[10] += pj * v2.z; acc[11] += pj * v2.w;
        acc[12] += pj * v3.x; acc[13] += pj * v3.y; acc[14] += pj * v3.z; acc[15] += pj * v3.w;
      }
    }
  }

  if (gi < N_SEQ) {
    const float inv = 1.0f / l;   // l>0 for all real rows except 2560 (overwritten by fix kernel)
    float* op = &O[(size_t)gi * DIMD + h * DHEAD + q4 * 16];
#pragma unroll
    for (int u = 0; u < 4; ++u) {
      float4 o;
      o.x = acc[u * 4 + 0] * inv;
      o.y = acc[u * 4 + 1] * inv;
      o.z = acc[u * 4 + 2] * inv;
      o.w = acc[u * 4 + 3] * inv;
      *(float4*)&op[u * 4] = o;
    }
  }
}

// ---------------- row 2560 (fully masked): uniform attention = mean of all V rows ----------------
__global__ void fix_row2560(const float* __restrict__ V, float* __restrict__ O) {
  const int e = blockIdx.x * 256 + threadIdx.x;  // 0..1023
  float s = 0.f;
  for (int j = 0; j < N_SEQ; ++j) s += V[(size_t)j * DIMD + e];
  O[(size_t)2560 * DIMD + e] = s * (1.0f / 2561.0f);
}

extern "C" void kernel_launch(void* const* d_in, const int* in_sizes, int n_in,
                              void* d_out, int out_size, void* d_ws, size_t ws_size,
                              hipStream_t stream) {
  const float* q  = (const float*)d_in[0];
  const float* k  = (const float*)d_in[1];
  const float* v  = (const float*)d_in[2];
  const float* Wq = (const float*)d_in[3];
  const float* Wk = (const float*)d_in[4];
  const float* Wv = (const float*)d_in[5];
  const float* Wo = (const float*)d_in[6];
  const float* bo = (const float*)d_in[7];
  float* out = (float*)d_out;

  const size_t seg = (size_t)NPAD * DIMD;  // 2,686,976 floats
  float* Qb = (float*)d_ws;
  float* Kb = Qb + seg;
  float* Vb = Kb + seg;
  float* Ob = Vb + seg;

  dim3 ggrid(16, 41);   // 16 col-tiles x 41 row-tiles
  // projections (Q gets the 1/sqrt(64) scale folded in)
  gemm64<<<ggrid, 256, 0, stream>>>(q, Wq, Qb, N_SEQ, NPAD, 0.125f, nullptr);
  gemm64<<<ggrid, 256, 0, stream>>>(k, Wk, Kb, N_SEQ, NPAD, 1.0f, nullptr);
  gemm64<<<ggrid, 256, 0, stream>>>(v, Wv, Vb, N_SEQ, NPAD, 1.0f, nullptr);

  attn64<<<dim3(41, NHEAD), 256, 0, stream>>>(Qb, Kb, Vb, Ob);
  fix_row2560<<<dim3(4), 256, 0, stream>>>(Vb, Ob);

  // output projection + bias
  gemm64<<<ggrid, 256, 0, stream>>>(Ob, Wo, out, N_SEQ, N_SEQ, 1.0f, bo);
}

// Round 2
// 197.901 us; speedup vs baseline: 4.5539x; 4.5539x over previous
//
#include <hip/hip_runtime.h>
#include <float.h>

#define N_SEQ 2561
#define NPAD  2688          // 21 * 128 = 42 * 64
#define SEG   ((size_t)NPAD * 1024)

typedef __attribute__((ext_vector_type(8))) short  short8;   // bf16x8 MFMA fragment
typedef __attribute__((ext_vector_type(4))) float  f32x4;
typedef __attribute__((ext_vector_type(4))) unsigned short u16x4;

__device__ __forceinline__ unsigned short f2bf(float f) {
  unsigned int u = __float_as_uint(f);
  u += 0x7FFFu + ((u >> 16) & 1u);          // round-to-nearest-even
  return (unsigned short)(u >> 16);
}
__device__ __forceinline__ float bf2f(unsigned short v) {
  return __uint_as_float(((unsigned int)v) << 16);
}
__device__ __forceinline__ f32x4 mfma16(short8 a, short8 b, f32x4 c) {
  return __builtin_amdgcn_mfma_f32_16x16x32_bf16(a, b, c, 0, 0, 0);
}
__device__ __forceinline__ void load_lds16(const void* g, void* l) {
  __builtin_amdgcn_global_load_lds((const __attribute__((address_space(1))) void*)g,
                                   (__attribute__((address_space(3))) void*)l, 16, 0, 0);
}

// ---------------- analytic mask (verified round 0) ----------------
__device__ __forceinline__ bool attend_ij(int i, int j) {
  if (i == 0) return j == 0;
  if (j == 0 || i > 2560 || j > 2560) return false;
  int qi = (i == 2560) ? 0 : i;
  int kj = j - 1;
  int t  = qi >> 8, tk = kj >> 8;
  if (tk > t || tk < t - 3) return false;
  int r  = (qi >> 4) & 15, c  = qi & 15;
  int rk = (kj >> 4) & 15, ck = kj & 15;
  int dr = rk - r, dc = ck - c;
  if (dr < -2 || dr > 2 || dc < -2 || dc > 2) return false;
  return (tk < t) || (dr < 0) || (dr == 0 && dc < 0);
}
__device__ __forceinline__ bool tile_live(int i0, int j0) {
  int qlo = max(i0, 1), qhi = min(i0 + 63, 2559);
  if (qlo > qhi) return false;
  int klo = max(j0 - 1, 0), khi = min(j0 + 62, 2559);
  int tq0 = qlo >> 8, tq1 = qhi >> 8;
  int tk0 = klo >> 8, tk1 = khi >> 8;
  if (tk0 > tq1 || tk1 < tq0 - 3) return false;
  int rq0 = 0, rq1 = 15;
  if (tq0 == tq1) { rq0 = (qlo >> 4) & 15; rq1 = (qhi >> 4) & 15; }
  int rk0 = 0, rk1 = 15;
  if (tk0 == tk1) { rk0 = (klo >> 4) & 15; rk1 = (khi >> 4) & 15; }
  if (rk0 > rq1 + 2 || rk1 < rq0 - 2) return false;
  return true;
}

// ---------------- fp32 -> bf16 conversion, rows >= N_SEQ zero-padded ----------------
__global__ __launch_bounds__(256) void cvt_x(const float* __restrict__ src,
                                             unsigned short* __restrict__ dst) {
  int idx = blockIdx.x * 256 + threadIdx.x;     // 344064 threads, 8 elems each
  size_t base = (size_t)idx * 8;
  int row = idx >> 7;
  short8 o;
  if (row < N_SEQ) {
    float4 a = *(const float4*)&src[base];
    float4 b = *(const float4*)&src[base + 4];
    o[0] = (short)f2bf(a.x); o[1] = (short)f2bf(a.y);
    o[2] = (short)f2bf(a.z); o[3] = (short)f2bf(a.w);
    o[4] = (short)f2bf(b.x); o[5] = (short)f2bf(b.y);
    o[6] = (short)f2bf(b.z); o[7] = (short)f2bf(b.w);
  } else {
    for (int j = 0; j < 8; ++j) o[j] = 0;
  }
  *(short8*)&dst[base] = o;
}

// ---------------- weight transpose + convert (1024x1024); z selects weight ----------------
__global__ __launch_bounds__(256) void cvt_wT(const float* __restrict__ W0, const float* __restrict__ W1,
                                              const float* __restrict__ W2, const float* __restrict__ W3,
                                              unsigned short* __restrict__ T0, unsigned short* __restrict__ T1,
                                              unsigned short* __restrict__ T2, unsigned short* __restrict__ T3) {
  const float* W; unsigned short* T; float scale = 1.0f;
  switch (blockIdx.z) {
    case 0: W = W0; T = T0; scale = 0.125f; break;   // fold 1/sqrt(64) into Wq
    case 1: W = W1; T = T1; break;
    case 2: W = W2; T = T2; break;
    default: W = W3; T = T3; break;
  }
  __shared__ float tls[64][65];
  const int r0 = blockIdx.y * 64, c0 = blockIdx.x * 64;
  const int tid = threadIdx.x, tr = tid >> 4, tc = tid & 15;
#pragma unroll
  for (int u = 0; u < 4; ++u) {
    int row = tr + u * 16;
    float4 v = *(const float4*)&W[(size_t)(r0 + row) * 1024 + c0 + tc * 4];
    tls[tc * 4 + 0][row] = v.x; tls[tc * 4 + 1][row] = v.y;
    tls[tc * 4 + 2][row] = v.z; tls[tc * 4 + 3][row] = v.w;
  }
  __syncthreads();
#pragma unroll
  for (int u = 0; u < 4; ++u) {
    int crow = tr + u * 16;
    u16x4 o;
#pragma unroll
    for (int j = 0; j < 4; ++j) o[j] = f2bf(tls[crow][tc * 4 + j] * scale);
    *(u16x4*)&T[(size_t)(c0 + crow) * 1024 + r0 + tc * 4] = o;
  }
}

// ---------------- bf16 MFMA GEMM: C[m][n] = sum_k A[m][k] * Bt[n][k] (+bias) ----------------
// A: [M][1024] bf16 row-major, Bt: [N][1024] bf16 row-major. 128x128 tile, 4 waves.
template <bool BF16OUT>
__global__ __launch_bounds__(256) void gemm_bt(const unsigned short* __restrict__ A,
                                               const unsigned short* __restrict__ Bt,
                                               void* __restrict__ Cv, int ldc, int rows_write,
                                               const float* __restrict__ bias) {
  __shared__ unsigned short Asm[128 * 64];
  __shared__ unsigned short Bsm[128 * 64];
  const int i0 = blockIdx.y * 128, c0 = blockIdx.x * 128;
  const int tid = threadIdx.x, w = tid >> 6, lane = tid & 63;
  const int wr = w >> 1, wc = w & 1;
  const int srow = lane >> 3;
  const int scol = ((lane & 7) * 8) ^ (srow << 3);   // pre-swizzled source col (elements)
  f32x4 acc[4][4] = {};

  for (int k0 = 0; k0 < 1024; k0 += 64) {
    __syncthreads();
#pragma unroll
    for (int u = 0; u < 4; ++u) {
      int row = w * 32 + u * 8 + srow;
      load_lds16(&A [(size_t)(i0 + row) * 1024 + k0 + scol], &Asm[(w * 32 + u * 8) * 64]);
      load_lds16(&Bt[(size_t)(c0 + row) * 1024 + k0 + scol], &Bsm[(w * 32 + u * 8) * 64]);
    }
    __syncthreads();
#pragma unroll
    for (int kk = 0; kk < 2; ++kk) {
      const int colel = kk * 32 + (lane >> 4) * 8;
      short8 af[4], bf[4];
#pragma unroll
      for (int m = 0; m < 4; ++m) {
        int row = wr * 64 + m * 16 + (lane & 15);
        af[m] = *(const short8*)&Asm[row * 64 + (colel ^ ((row & 7) << 3))];
      }
#pragma unroll
      for (int n = 0; n < 4; ++n) {
        int row = wc * 64 + n * 16 + (lane & 15);
        bf[n] = *(const short8*)&Bsm[row * 64 + (colel ^ ((row & 7) << 3))];
      }
#pragma unroll
      for (int m = 0; m < 4; ++m)
#pragma unroll
        for (int n = 0; n < 4; ++n)
          acc[m][n] = mfma16(af[m], bf[n], acc[m][n]);
    }
  }

#pragma unroll
  for (int m = 0; m < 4; ++m)
#pragma unroll
    for (int n = 0; n < 4; ++n) {
      const int col = c0 + wc * 64 + n * 16 + (lane & 15);
#pragma unroll
      for (int r = 0; r < 4; ++r) {
        const int row = i0 + wr * 64 + m * 16 + (lane >> 4) * 4 + r;
        if (BF16OUT) {
          ((unsigned short*)Cv)[(size_t)row * ldc + col] = f2bf(acc[m][n][r]);
        } else if (row < rows_write) {
          ((float*)Cv)[(size_t)row * ldc + col] = acc[m][n][r] + bias[col];
        }
      }
    }
}

// ---------------- MFMA flash attention ----------------
// Qb,Kb: [NPAD][1024] bf16 (head h at cols h*64..); Vt: [1024][NPAD] bf16; Ob: [NPAD][1024] bf16
__global__ __launch_bounds__(256) void attn_mfma(const unsigned short* __restrict__ Qb,
                                                 const unsigned short* __restrict__ Kb,
                                                 const unsigned short* __restrict__ Vt,
                                                 unsigned short* __restrict__ Ob) {
  __shared__ unsigned short Ksm[64 * 64];
  __shared__ unsigned short Vsm[64 * 64];
  __shared__ unsigned short Psm[4][16 * 72];
  const int i0 = blockIdx.x * 64, h = blockIdx.y;
  const int tid = threadIdx.x, w = tid >> 6, lane = tid & 63;
  const int srow = lane >> 3;
  const int scol = ((lane & 7) * 8) ^ (srow << 3);

  // Q fragments hoisted (loop-invariant)
  short8 qf[2];
  {
    const int qrow = i0 + w * 16 + (lane & 15);
#pragma unroll
    for (int kk = 0; kk < 2; ++kk)
      qf[kk] = *(const short8*)&Qb[(size_t)qrow * 1024 + h * 64 + kk * 32 + (lane >> 4) * 8];
  }

  f32x4 acc[4] = {};
  float mrow[4], lrow[4];
#pragma unroll
  for (int r = 0; r < 4; ++r) { mrow[r] = -FLT_MAX; lrow[r] = 0.f; }
  const int qr0 = i0 + w * 16 + (lane >> 4) * 4;

  for (int jt = 0; jt < 42; ++jt) {
    const int j0 = jt * 64;
    if (!tile_live(i0, j0)) continue;

    __syncthreads();
#pragma unroll
    for (int u = 0; u < 2; ++u) {
      int row = w * 16 + u * 8 + srow;
      load_lds16(&Kb[(size_t)(j0 + row) * 1024 + h * 64 + scol], &Ksm[(w * 16 + u * 8) * 64]);
      load_lds16(&Vt[(size_t)(h * 64 + row) * NPAD + j0 + scol], &Vsm[(w * 16 + u * 8) * 64]);
    }
    __syncthreads();

    // S = Q K^T  (16 q-rows x 64 keys per wave)
    f32x4 s[4] = {};
#pragma unroll
    for (int kk = 0; kk < 2; ++kk) {
      const int colel = kk * 32 + (lane >> 4) * 8;
#pragma unroll
      for (int n = 0; n < 4; ++n) {
        int row = n * 16 + (lane & 15);
        short8 kf = *(const short8*)&Ksm[row * 64 + (colel ^ ((row & 7) << 3))];
        s[n] = mfma16(qf[kk], kf, s[n]);
      }
    }

    // mask + online softmax (rows owned per-lane-group, replicated over 16 lanes)
    float p[4][4], rm[4];
#pragma unroll
    for (int r = 0; r < 4; ++r) rm[r] = -FLT_MAX;
#pragma unroll
    for (int n = 0; n < 4; ++n) {
      const int kcol = j0 + n * 16 + (lane & 15);
#pragma unroll
      for (int r = 0; r < 4; ++r) {
        float v = attend_ij(qr0 + r, kcol) ? s[n][r] : -FLT_MAX;
        p[n][r] = v;
        rm[r] = fmaxf(rm[r], v);
      }
    }
#pragma unroll
    for (int r = 0; r < 4; ++r) {
      rm[r] = fmaxf(rm[r], __shfl_xor(rm[r], 1));
      rm[r] = fmaxf(rm[r], __shfl_xor(rm[r], 2));
      rm[r] = fmaxf(rm[r], __shfl_xor(rm[r], 4));
      rm[r] = fmaxf(rm[r], __shfl_xor(rm[r], 8));
      float mn = fmaxf(mrow[r], rm[r]);
      float f = __expf(mrow[r] - mn);
      mrow[r] = mn;
      float ps = 0.f;
#pragma unroll
      for (int n = 0; n < 4; ++n) {
        float pv = __expf(p[n][r] - mn);
        p[n][r] = pv;
        ps += pv;
      }
      ps += __shfl_xor(ps, 1); ps += __shfl_xor(ps, 2);
      ps += __shfl_xor(ps, 4); ps += __shfl_xor(ps, 8);
      lrow[r] = lrow[r] * f + ps;
#pragma unroll
      for (int n = 0; n < 4; ++n) acc[n][r] *= f;
    }

    // P -> LDS (wave-private, padded ld=72), then PV
    unsigned short* Pw = &Psm[w][0];
#pragma unroll
    for (int n = 0; n < 4; ++n)
#pragma unroll
      for (int r = 0; r < 4; ++r)
        Pw[((lane >> 4) * 4 + r) * 72 + n * 16 + (lane & 15)] = f2bf(p[n][r]);

#pragma unroll
    for (int kk = 0; kk < 2; ++kk) {
      short8 pf = *(const short8*)&Pw[(lane & 15) * 72 + kk * 32 + (lane >> 4) * 8];
      const int colel = kk * 32 + (lane >> 4) * 8;
#pragma unroll
      for (int n = 0; n < 4; ++n) {
        int row = n * 16 + (lane & 15);
        short8 vf = *(const short8*)&Vsm[row * 64 + (colel ^ ((row & 7) << 3))];
        acc[n] = mfma16(pf, vf, acc[n]);
      }
    }
  }

#pragma unroll
  for (int r = 0; r < 4; ++r) {
    const int row = qr0 + r;
    if (row < N_SEQ) {
      const float inv = 1.0f / lrow[r];   // row 2560: 0/0 -> NaN, overwritten by fix kernel
#pragma unroll
      for (int n = 0; n < 4; ++n)
        Ob[(size_t)row * 1024 + h * 64 + n * 16 + (lane & 15)] = f2bf(acc[n][r] * inv);
    }
  }
}

// ---------------- row 2560: uniform attention = mean over all 2561 V rows ----------------
__global__ void fix_row2560(const unsigned short* __restrict__ Vt, unsigned short* __restrict__ Ob) {
  const int d = blockIdx.x, lane = threadIdx.x;   // 1024 blocks x 64 threads
  float s = 0.f;
  for (int j = lane; j < N_SEQ; j += 64) s += bf2f(Vt[(size_t)d * NPAD + j]);
  s += __shfl_xor(s, 1);  s += __shfl_xor(s, 2);  s += __shfl_xor(s, 4);
  s += __shfl_xor(s, 8);  s += __shfl_xor(s, 16); s += __shfl_xor(s, 32);
  if (lane == 0) Ob[(size_t)2560 * 1024 + d] = f2bf(s * (1.0f / 2561.0f));
}

extern "C" void kernel_launch(void* const* d_in, const int* in_sizes, int n_in,
                              void* d_out, int out_size, void* d_ws, size_t ws_size,
                              hipStream_t stream) {
  const float* q  = (const float*)d_in[0];
  const float* k  = (const float*)d_in[1];
  const float* v  = (const float*)d_in[2];
  const float* Wq = (const float*)d_in[3];
  const float* Wk = (const float*)d_in[4];
  const float* Wv = (const float*)d_in[5];
  const float* Wo = (const float*)d_in[6];
  const float* bo = (const float*)d_in[7];

  unsigned short* ws = (unsigned short*)d_ws;
  const size_t MW = (size_t)1024 * 1024;
  unsigned short* Xq  = ws;            // [NPAD][1024]
  unsigned short* Xk  = ws + SEG;
  unsigned short* Xv  = ws + 2 * SEG;
  unsigned short* Qb  = ws + 3 * SEG;
  unsigned short* Kb  = ws + 4 * SEG;
  unsigned short* VtB = ws + 5 * SEG;  // [1024][NPAD]
  unsigned short* WqT = ws + 6 * SEG;
  unsigned short* WkT = WqT + MW;
  unsigned short* WvT = WqT + 2 * MW;
  unsigned short* WoT = WqT + 3 * MW;
  unsigned short* ObB = Xq;            // reuse Xq after Q-projection

  cvt_x<<<1344, 256, 0, stream>>>(q, Xq);
  cvt_x<<<1344, 256, 0, stream>>>(k, Xk);
  cvt_x<<<1344, 256, 0, stream>>>(v, Xv);
  cvt_wT<<<dim3(16, 16, 4), 256, 0, stream>>>(Wq, Wk, Wv, Wo, WqT, WkT, WvT, WoT);

  gemm_bt<true><<<dim3(8, 21), 256, 0, stream>>>(Xq, WqT, Qb, 1024, 0, nullptr);
  gemm_bt<true><<<dim3(8, 21), 256, 0, stream>>>(Xk, WkT, Kb, 1024, 0, nullptr);
  gemm_bt<true><<<dim3(21, 8), 256, 0, stream>>>(WvT, Xv, VtB, NPAD, 0, nullptr);  // C = V^T

  attn_mfma<<<dim3(42, 16), 256, 0, stream>>>(Qb, Kb, VtB, ObB);
  fix_row2560<<<1024, 64, 0, stream>>>(VtB, ObB);

  gemm_bt<false><<<dim3(8, 21), 256, 0, stream>>>(ObB, WoT, d_out, 1024, N_SEQ, bo);
}

// Round 3
// 147.730 us; speedup vs baseline: 6.1004x; 1.3396x over previous
//
#include <hip/hip_runtime.h>
#include <float.h>

#define N_SEQ 2561
#define NPAD  2688          // 21 * 128 = 42 * 64 = 168 * 16
#define SEG   ((size_t)NPAD * 1024)

typedef __attribute__((ext_vector_type(8))) short  short8;
typedef __attribute__((ext_vector_type(4))) float  f32x4;
typedef __attribute__((ext_vector_type(4))) unsigned short u16x4;

__device__ __forceinline__ unsigned short f2bf(float f) {
  unsigned int u = __float_as_uint(f);
  u += 0x7FFFu + ((u >> 16) & 1u);
  return (unsigned short)(u >> 16);
}
__device__ __forceinline__ float bf2f(unsigned short v) {
  return __uint_as_float(((unsigned int)v) << 16);
}
__device__ __forceinline__ f32x4 mfma16(short8 a, short8 b, f32x4 c) {
  return __builtin_amdgcn_mfma_f32_16x16x32_bf16(a, b, c, 0, 0, 0);
}
__device__ __forceinline__ void load_lds16(const void* g, void* l) {
  __builtin_amdgcn_global_load_lds((const __attribute__((address_space(1))) void*)g,
                                   (__attribute__((address_space(3))) void*)l, 16, 0, 0);
}

// ---------------- analytic mask (verified rounds 0-1) ----------------
__device__ __forceinline__ bool attend_ij(int i, int j) {
  if (i == 0) return j == 0;
  if (j == 0 || i > 2560 || j > 2560) return false;
  int qi = (i == 2560) ? 0 : i;
  int kj = j - 1;
  int t  = qi >> 8, tk = kj >> 8;
  if (tk > t || tk < t - 3) return false;
  int r  = (qi >> 4) & 15, c  = qi & 15;
  int rk = (kj >> 4) & 15, ck = kj & 15;
  int dr = rk - r, dc = ck - c;
  if (dr < -2 || dr > 2 || dc < -2 || dc > 2) return false;
  return (tk < t) || (dr < 0) || (dr == 0 && dc < 0);
}

// mask64[i][jt] bit b = attend(i, jt*64+b)
__global__ __launch_bounds__(256) void setup_mask(unsigned long long* __restrict__ mask64) {
  int idx = blockIdx.x * 256 + threadIdx.x;
  if (idx >= 2688 * 42) return;
  int i = idx / 42, jt = idx - i * 42;
  unsigned long long m = 0;
#pragma unroll 4
  for (int b = 0; b < 64; ++b)
    if (attend_ij(i, jt * 64 + b)) m |= (1ull << b);
  mask64[idx] = m;
}

// anyN[qg][jt] nibble: bit n set iff any of 16 rows has a live key in cols n*16..n*16+15
__global__ __launch_bounds__(256) void setup_any(const unsigned long long* __restrict__ mask64,
                                                 unsigned char* __restrict__ anyN) {
  int idx = blockIdx.x * 256 + threadIdx.x;
  if (idx >= 168 * 42) return;
  int qg = idx / 42, jt = idx - qg * 42;
  unsigned long long o = 0;
  for (int r = 0; r < 16; ++r) o |= mask64[(size_t)(qg * 16 + r) * 42 + jt];
  unsigned char b = 0;
  if (o & 0xFFFFull)            b |= 1;
  if (o & 0xFFFF0000ull)        b |= 2;
  if ((o >> 32) & 0xFFFFull)    b |= 4;
  if (o >> 48)                  b |= 8;
  anyN[idx] = b;
}

// ---------------- fp32 -> bf16, rows >= N_SEQ zeroed; q,k,v in one launch ----------------
__global__ __launch_bounds__(256) void cvt_x3(const float* __restrict__ q, const float* __restrict__ k,
                                              const float* __restrict__ v,
                                              unsigned short* __restrict__ Xq, unsigned short* __restrict__ Xk,
                                              unsigned short* __restrict__ Xv) {
  const float* src = (blockIdx.y == 0) ? q : (blockIdx.y == 1) ? k : v;
  unsigned short* dst = (blockIdx.y == 0) ? Xq : (blockIdx.y == 1) ? Xk : Xv;
  int idx = blockIdx.x * 256 + threadIdx.x;
  size_t base = (size_t)idx * 8;
  int row = idx >> 7;
  short8 o;
  if (row < N_SEQ) {
    float4 a = *(const float4*)&src[base];
    float4 b = *(const float4*)&src[base + 4];
    o[0] = (short)f2bf(a.x); o[1] = (short)f2bf(a.y);
    o[2] = (short)f2bf(a.z); o[3] = (short)f2bf(a.w);
    o[4] = (short)f2bf(b.x); o[5] = (short)f2bf(b.y);
    o[6] = (short)f2bf(b.z); o[7] = (short)f2bf(b.w);
  } else {
    for (int j = 0; j < 8; ++j) o[j] = 0;
  }
  *(short8*)&dst[base] = o;
}

// ---------------- weight transpose + convert ----------------
__global__ __launch_bounds__(256) void cvt_wT(const float* __restrict__ W0, const float* __restrict__ W1,
                                              const float* __restrict__ W2, const float* __restrict__ W3,
                                              unsigned short* __restrict__ T0, unsigned short* __restrict__ T1,
                                              unsigned short* __restrict__ T2, unsigned short* __restrict__ T3) {
  const float* W; unsigned short* T; float scale = 1.0f;
  switch (blockIdx.z) {
    case 0: W = W0; T = T0; scale = 0.125f; break;
    case 1: W = W1; T = T1; break;
    case 2: W = W2; T = T2; break;
    default: W = W3; T = T3; break;
  }
  __shared__ float tls[64][65];
  const int r0 = blockIdx.y * 64, c0 = blockIdx.x * 64;
  const int tid = threadIdx.x, tr = tid >> 4, tc = tid & 15;
#pragma unroll
  for (int u = 0; u < 4; ++u) {
    int row = tr + u * 16;
    float4 v = *(const float4*)&W[(size_t)(r0 + row) * 1024 + c0 + tc * 4];
    tls[tc * 4 + 0][row] = v.x; tls[tc * 4 + 1][row] = v.y;
    tls[tc * 4 + 2][row] = v.z; tls[tc * 4 + 3][row] = v.w;
  }
  __syncthreads();
#pragma unroll
  for (int u = 0; u < 4; ++u) {
    int crow = tr + u * 16;
    u16x4 o;
#pragma unroll
    for (int j = 0; j < 4; ++j) o[j] = f2bf(tls[crow][tc * 4 + j] * scale);
    *(u16x4*)&T[(size_t)(c0 + crow) * 1024 + r0 + tc * 4] = o;
  }
}

// ---------------- 2-phase double-buffered bf16 GEMM core: C = A * Bt^T ----------------
__device__ __forceinline__ void stage_tile(const unsigned short* A, const unsigned short* Bt,
                                           unsigned short* Asm, unsigned short* Bsm,
                                           int i0, int c0, int k0, int w, int srow, int scol) {
#pragma unroll
  for (int u = 0; u < 4; ++u) {
    int row = w * 32 + u * 8 + srow;
    load_lds16(&A [(size_t)(i0 + row) * 1024 + k0 + scol], &Asm[(w * 32 + u * 8) * 64]);
    load_lds16(&Bt[(size_t)(c0 + row) * 1024 + k0 + scol], &Bsm[(w * 32 + u * 8) * 64]);
  }
}

template <int BF16OUT>
__device__ __forceinline__ void gemm_core(const unsigned short* A, const unsigned short* Bt,
                                          void* Cv, int ldc, int i0, int c0, int rows_write,
                                          const float* bias, unsigned short* Asm, unsigned short* Bsm) {
  const int tid = threadIdx.x, w = tid >> 6, lane = tid & 63;
  const int wr = w >> 1, wc = w & 1;
  const int srow = lane >> 3;
  const int scol = ((lane & 7) * 8) ^ (srow << 3);
  f32x4 acc[4][4] = {};

  stage_tile(A, Bt, Asm, Bsm, i0, c0, 0, w, srow, scol);   // prologue -> buf0

  for (int t = 0; t < 16; ++t) {
    __syncthreads();                                        // drains vmcnt -> buf(t&1) ready
    if (t < 15)
      stage_tile(A, Bt, Asm + ((t + 1) & 1) * 8192, Bsm + ((t + 1) & 1) * 8192,
                 i0, c0, (t + 1) * 64, w, srow, scol);      // overlaps with compute below
    const unsigned short* Ab = Asm + (t & 1) * 8192;
    const unsigned short* Bb = Bsm + (t & 1) * 8192;
#pragma unroll
    for (int kk = 0; kk < 2; ++kk) {
      const int colel = kk * 32 + (lane >> 4) * 8;
      short8 af[4], bf[4];
#pragma unroll
      for (int m = 0; m < 4; ++m) {
        int row = wr * 64 + m * 16 + (lane & 15);
        af[m] = *(const short8*)&Ab[row * 64 + (colel ^ ((row & 7) << 3))];
      }
#pragma unroll
      for (int n = 0; n < 4; ++n) {
        int row = wc * 64 + n * 16 + (lane & 15);
        bf[n] = *(const short8*)&Bb[row * 64 + (colel ^ ((row & 7) << 3))];
      }
#pragma unroll
      for (int m = 0; m < 4; ++m)
#pragma unroll
        for (int n = 0; n < 4; ++n)
          acc[m][n] = mfma16(af[m], bf[n], acc[m][n]);
    }
  }

#pragma unroll
  for (int m = 0; m < 4; ++m)
#pragma unroll
    for (int n = 0; n < 4; ++n) {
      const int col = c0 + wc * 64 + n * 16 + (lane & 15);
#pragma unroll
      for (int r = 0; r < 4; ++r) {
        const int row = i0 + wr * 64 + m * 16 + (lane >> 4) * 4 + r;
        if (BF16OUT) {
          ((unsigned short*)Cv)[(size_t)row * ldc + col] = f2bf(acc[m][n][r]);
        } else if (row < rows_write) {
          ((float*)Cv)[(size_t)row * ldc + col] = acc[m][n][r] + bias[col];
        }
      }
    }
}

// three projection GEMMs in one launch (504 blocks)
__global__ __launch_bounds__(256) void proj3(const unsigned short* __restrict__ Xq, const unsigned short* __restrict__ WqT, unsigned short* __restrict__ Qb,
                                             const unsigned short* __restrict__ Xk, const unsigned short* __restrict__ WkT, unsigned short* __restrict__ Kb,
                                             const unsigned short* __restrict__ WvT, const unsigned short* __restrict__ Xv, unsigned short* __restrict__ VtB) {
  __shared__ unsigned short Asm[2 * 8192];
  __shared__ unsigned short Bsm[2 * 8192];
  int b = blockIdx.x;
  const unsigned short *A, *Bt; unsigned short* C; int ldc, i0, c0;
  if (b < 168)      { int r = b;       A = Xq;  Bt = WqT; C = Qb;  ldc = 1024; i0 = (r >> 3) * 128; c0 = (r & 7) * 128; }
  else if (b < 336) { int r = b - 168; A = Xk;  Bt = WkT; C = Kb;  ldc = 1024; i0 = (r >> 3) * 128; c0 = (r & 7) * 128; }
  else              { int r = b - 336; A = WvT; Bt = Xv;  C = VtB; ldc = NPAD; i0 = (r / 21) * 128; c0 = (r % 21) * 128; }
  gemm_core<1>(A, Bt, C, ldc, i0, c0, 0, nullptr, Asm, Bsm);
}

__global__ __launch_bounds__(256) void outproj(const unsigned short* __restrict__ Ob, const unsigned short* __restrict__ WoT,
                                               float* __restrict__ out, const float* __restrict__ bias) {
  __shared__ unsigned short Asm[2 * 8192];
  __shared__ unsigned short Bsm[2 * 8192];
  int b = blockIdx.x;
  gemm_core<0>(Ob, WoT, out, 1024, (b >> 3) * 128, (b & 7) * 128, N_SEQ, bias, Asm, Bsm);
}

// ---------------- barrier-free MFMA flash attention ----------------
__global__ __launch_bounds__(256) void attn_mfma2(const unsigned short* __restrict__ Qb,
                                                  const unsigned short* __restrict__ Kb,
                                                  const unsigned short* __restrict__ Vt,
                                                  unsigned short* __restrict__ Ob,
                                                  const unsigned long long* __restrict__ mask64,
                                                  const unsigned char* __restrict__ anyN) {
  __shared__ unsigned short Psm[4][16 * 72];
  const int h = blockIdx.y;
  const int tid = threadIdx.x, w = tid >> 6, lane = tid & 63;
  const int qg = blockIdx.x * 4 + w;          // 0..167, one image row of queries
  const int lhi = lane >> 4, llo = lane & 15;
  unsigned short* Pw = &Psm[w][0];

  short8 qf[2];
  {
    const size_t qrow = (size_t)(qg * 16 + llo) * 1024 + h * 64 + lhi * 8;
    qf[0] = *(const short8*)&Qb[qrow];
    qf[1] = *(const short8*)&Qb[qrow + 32];
  }
  const int qr0 = qg * 16 + lhi * 4;

  f32x4 acc[4] = {};
  float mrow[4], lrow[4];
#pragma unroll
  for (int r = 0; r < 4; ++r) { mrow[r] = -FLT_MAX; lrow[r] = 0.f; }

  for (int jt = 0; jt < 42; ++jt) {
    int anyn = anyN[qg * 42 + jt];
    anyn = __builtin_amdgcn_readfirstlane(anyn);
    if (!anyn) continue;
    const int j0 = jt * 64;

    unsigned long long mr[4];
#pragma unroll
    for (int r = 0; r < 4; ++r) mr[r] = mask64[(size_t)(qr0 + r) * 42 + jt];

    // S = Q K^T per live 16-key group
    f32x4 s[4];
#pragma unroll
    for (int n = 0; n < 4; ++n) {
      if (anyn & (1 << n)) {
        const unsigned short* kb = &Kb[(size_t)(j0 + n * 16 + llo) * 1024 + h * 64 + lhi * 8];
        short8 kf0 = *(const short8*)&kb[0];
        short8 kf1 = *(const short8*)&kb[32];
        f32x4 z = {0.f, 0.f, 0.f, 0.f};
        z = mfma16(qf[0], kf0, z);
        s[n] = mfma16(qf[1], kf1, z);
      }
    }

    // mask + online softmax
    float p[4][4];
#pragma unroll
    for (int r = 0; r < 4; ++r) {
      float rm = -FLT_MAX;
#pragma unroll
      for (int n = 0; n < 4; ++n) {
        if (anyn & (1 << n)) {
          float v = ((mr[r] >> (n * 16 + llo)) & 1ull) ? s[n][r] : -FLT_MAX;
          p[n][r] = v;
          rm = fmaxf(rm, v);
        }
      }
      rm = fmaxf(rm, __shfl_xor(rm, 1));
      rm = fmaxf(rm, __shfl_xor(rm, 2));
      rm = fmaxf(rm, __shfl_xor(rm, 4));
      rm = fmaxf(rm, __shfl_xor(rm, 8));
      const float mn = fmaxf(mrow[r], rm);
      const float f = __expf(mrow[r] - mn);
      float ps = 0.f;
#pragma unroll
      for (int n = 0; n < 4; ++n) {
        if (anyn & (1 << n)) {
          float pv = __expf(p[n][r] - mn);
          p[n][r] = pv;
          ps += pv;
        } else {
          p[n][r] = 0.f;
        }
      }
      ps += __shfl_xor(ps, 1); ps += __shfl_xor(ps, 2);
      ps += __shfl_xor(ps, 4); ps += __shfl_xor(ps, 8);
      lrow[r] = lrow[r] * f + ps;
      mrow[r] = mn;
      acc[0][r] *= f; acc[1][r] *= f; acc[2][r] *= f; acc[3][r] *= f;
    }

    // P -> wave-private LDS
#pragma unroll
    for (int n = 0; n < 4; ++n)
#pragma unroll
      for (int r = 0; r < 4; ++r)
        Pw[(lhi * 4 + r) * 72 + n * 16 + llo] = f2bf(p[n][r]);

    // PV (skip dead 32-key halves)
#pragma unroll
    for (int kk = 0; kk < 2; ++kk) {
      if (!(anyn & (kk ? 12 : 3))) continue;
      short8 pf = *(const short8*)&Pw[llo * 72 + kk * 32 + lhi * 8];
#pragma unroll
      for (int n = 0; n < 4; ++n) {
        short8 vf = *(const short8*)&Vt[(size_t)(h * 64 + n * 16 + llo) * NPAD + j0 + kk * 32 + lhi * 8];
        acc[n] = mfma16(pf, vf, acc[n]);
      }
    }
  }

#pragma unroll
  for (int r = 0; r < 4; ++r) {
    const int row = qr0 + r;
    if (row < N_SEQ) {
      const float inv = 1.0f / lrow[r];   // row 2560 -> NaN, overwritten by fix kernel
#pragma unroll
      for (int n = 0; n < 4; ++n)
        Ob[(size_t)row * 1024 + h * 64 + n * 16 + llo] = f2bf(acc[n][r] * inv);
    }
  }
}

// ---------------- row 2560: uniform attention = mean over all 2561 V rows ----------------
__global__ void fix_row2560(const unsigned short* __restrict__ Vt, unsigned short* __restrict__ Ob) {
  const int d = blockIdx.x, lane = threadIdx.x;
  float s = 0.f;
  for (int j = lane; j < N_SEQ; j += 64) s += bf2f(Vt[(size_t)d * NPAD + j]);
  s += __shfl_xor(s, 1);  s += __shfl_xor(s, 2);  s += __shfl_xor(s, 4);
  s += __shfl_xor(s, 8);  s += __shfl_xor(s, 16); s += __shfl_xor(s, 32);
  if (lane == 0) Ob[(size_t)2560 * 1024 + d] = f2bf(s * (1.0f / 2561.0f));
}

extern "C" void kernel_launch(void* const* d_in, const int* in_sizes, int n_in,
                              void* d_out, int out_size, void* d_ws, size_t ws_size,
                              hipStream_t stream) {
  const float* q  = (const float*)d_in[0];
  const float* k  = (const float*)d_in[1];
  const float* v  = (const float*)d_in[2];
  const float* Wq = (const float*)d_in[3];
  const float* Wk = (const float*)d_in[4];
  const float* Wv = (const float*)d_in[5];
  const float* Wo = (const float*)d_in[6];
  const float* bo = (const float*)d_in[7];

  unsigned short* ws = (unsigned short*)d_ws;
  const size_t MW = (size_t)1024 * 1024;
  unsigned short* Xq  = ws;
  unsigned short* Xk  = ws + SEG;
  unsigned short* Xv  = ws + 2 * SEG;
  unsigned short* Qb  = ws + 3 * SEG;
  unsigned short* Kb  = ws + 4 * SEG;
  unsigned short* VtB = ws + 5 * SEG;
  unsigned short* WqT = ws + 6 * SEG;
  unsigned short* WkT = WqT + MW;
  unsigned short* WvT = WqT + 2 * MW;
  unsigned short* WoT = WqT + 3 * MW;
  unsigned long long* mask64 = (unsigned long long*)(WqT + 4 * MW);
  unsigned char* anyN = (unsigned char*)(mask64 + 2688 * 42);
  unsigned short* ObB = Xq;            // reuse Xq after projections

  setup_mask<<<441, 256, 0, stream>>>(mask64);
  setup_any<<<28, 256, 0, stream>>>(mask64, anyN);
  cvt_x3<<<dim3(1344, 3), 256, 0, stream>>>(q, k, v, Xq, Xk, Xv);
  cvt_wT<<<dim3(16, 16, 4), 256, 0, stream>>>(Wq, Wk, Wv, Wo, WqT, WkT, WvT, WoT);

  proj3<<<504, 256, 0, stream>>>(Xq, WqT, Qb, Xk, WkT, Kb, WvT, Xv, VtB);

  attn_mfma2<<<dim3(42, 16), 256, 0, stream>>>(Qb, Kb, VtB, ObB, mask64, anyN);
  fix_row2560<<<1024, 64, 0, stream>>>(VtB, ObB);

  outproj<<<168, 256, 0, stream>>>(ObB, WoT, (float*)d_out, bo);
}

// Round 5
// 146.154 us; speedup vs baseline: 6.1662x; 1.0108x over previous
//
#include <hip/hip_runtime.h>
#include <float.h>

#define N_SEQ 2561
#define NPAD  2688          // 21 * 128 = 42 * 64 = 168 * 16
#define SEG   ((size_t)NPAD * 1024)
#define LOG2E 1.44269504088896340736f

typedef __attribute__((ext_vector_type(8))) short  short8;
typedef __attribute__((ext_vector_type(4))) short  s16x4;
typedef __attribute__((ext_vector_type(4))) float  f32x4;
typedef __attribute__((ext_vector_type(4))) unsigned int u32x4;
typedef __attribute__((ext_vector_type(4))) unsigned short u16x4;

__device__ __forceinline__ unsigned short f2bf(float f) {
  unsigned int u = __float_as_uint(f);
  u += 0x7FFFu + ((u >> 16) & 1u);
  return (unsigned short)(u >> 16);
}
__device__ __forceinline__ float bf2f(unsigned short v) {
  return __uint_as_float(((unsigned int)v) << 16);
}
__device__ __forceinline__ f32x4 mfma16(short8 a, short8 b, f32x4 c) {
  return __builtin_amdgcn_mfma_f32_16x16x32_bf16(a, b, c, 0, 0, 0);
}
__device__ __forceinline__ void load_lds16(const void* g, void* l) {
  __builtin_amdgcn_global_load_lds((const __attribute__((address_space(1))) void*)g,
                                   (__attribute__((address_space(3))) void*)l, 16, 0, 0);
}
__device__ __forceinline__ unsigned int cvt_pk_bf16(float a, float b) {
  unsigned int r;
  asm("v_cvt_pk_bf16_f32 %0, %1, %2" : "=v"(r) : "v"(a), "v"(b));
  return r;
}
__device__ __forceinline__ float fast_exp2(float x) {
  return __builtin_amdgcn_exp2f(x);
}

// ---------------- analytic mask (verified rounds 0-2) ----------------
__device__ __forceinline__ bool attend_ij(int i, int j) {
  if (i == 0) return j == 0;
  if (j == 0 || i > 2560 || j > 2560) return false;
  int qi = (i == 2560) ? 0 : i;
  int kj = j - 1;
  int t  = qi >> 8, tk = kj >> 8;
  if (tk > t || tk < t - 3) return false;
  int r  = (qi >> 4) & 15, c  = qi & 15;
  int rk = (kj >> 4) & 15, ck = kj & 15;
  int dr = rk - r, dc = ck - c;
  if (dr < -2 || dr > 2 || dc < -2 || dc > 2) return false;
  return (tk < t) || (dr < 0) || (dr == 0 && dc < 0);
}

__global__ __launch_bounds__(256) void setup_mask(unsigned long long* __restrict__ mask64) {
  int idx = blockIdx.x * 256 + threadIdx.x;
  if (idx >= 2688 * 42) return;
  int i = idx / 42, jt = idx - i * 42;
  unsigned long long m = 0;
#pragma unroll 4
  for (int b = 0; b < 64; ++b)
    if (attend_ij(i, jt * 64 + b)) m |= (1ull << b);
  mask64[idx] = m;
}

__global__ __launch_bounds__(256) void setup_any(const unsigned long long* __restrict__ mask64,
                                                 unsigned char* __restrict__ anyN) {
  int idx = blockIdx.x * 256 + threadIdx.x;
  if (idx >= 168 * 42) return;
  int qg = idx / 42, jt = idx - qg * 42;
  unsigned long long o = 0;
  for (int r = 0; r < 16; ++r) o |= mask64[(size_t)(qg * 16 + r) * 42 + jt];
  unsigned char b = 0;
  if (o & 0xFFFFull)            b |= 1;
  if (o & 0xFFFF0000ull)        b |= 2;
  if ((o >> 32) & 0xFFFFull)    b |= 4;
  if (o >> 48)                  b |= 8;
  anyN[idx] = b;
}

// ---------------- fp32 -> bf16, rows >= N_SEQ zeroed ----------------
__global__ __launch_bounds__(256) void cvt_x3(const float* __restrict__ q, const float* __restrict__ k,
                                              const float* __restrict__ v,
                                              unsigned short* __restrict__ Xq, unsigned short* __restrict__ Xk,
                                              unsigned short* __restrict__ Xv) {
  const float* src = (blockIdx.y == 0) ? q : (blockIdx.y == 1) ? k : v;
  unsigned short* dst = (blockIdx.y == 0) ? Xq : (blockIdx.y == 1) ? Xk : Xv;
  int idx = blockIdx.x * 256 + threadIdx.x;
  size_t base = (size_t)idx * 8;
  int row = idx >> 7;
  short8 o;
  if (row < N_SEQ) {
    float4 a = *(const float4*)&src[base];
    float4 b = *(const float4*)&src[base + 4];
    o[0] = (short)f2bf(a.x); o[1] = (short)f2bf(a.y);
    o[2] = (short)f2bf(a.z); o[3] = (short)f2bf(a.w);
    o[4] = (short)f2bf(b.x); o[5] = (short)f2bf(b.y);
    o[6] = (short)f2bf(b.z); o[7] = (short)f2bf(b.w);
  } else {
    for (int j = 0; j < 8; ++j) o[j] = 0;
  }
  *(short8*)&dst[base] = o;
}

// ---------------- weight transpose + convert ----------------
__global__ __launch_bounds__(256) void cvt_wT(const float* __restrict__ W0, const float* __restrict__ W1,
                                              const float* __restrict__ W2, const float* __restrict__ W3,
                                              unsigned short* __restrict__ T0, unsigned short* __restrict__ T1,
                                              unsigned short* __restrict__ T2, unsigned short* __restrict__ T3) {
  const float* W; unsigned short* T; float scale = 1.0f;
  switch (blockIdx.z) {
    case 0: W = W0; T = T0; scale = 0.125f * LOG2E; break;   // 1/sqrt(64) * log2e folded into Wq
    case 1: W = W1; T = T1; break;
    case 2: W = W2; T = T2; break;
    default: W = W3; T = T3; break;
  }
  __shared__ float tls[64][65];
  const int r0 = blockIdx.y * 64, c0 = blockIdx.x * 64;
  const int tid = threadIdx.x, tr = tid >> 4, tc = tid & 15;
#pragma unroll
  for (int u = 0; u < 4; ++u) {
    int row = tr + u * 16;
    float4 v = *(const float4*)&W[(size_t)(r0 + row) * 1024 + c0 + tc * 4];
    tls[tc * 4 + 0][row] = v.x; tls[tc * 4 + 1][row] = v.y;
    tls[tc * 4 + 2][row] = v.z; tls[tc * 4 + 3][row] = v.w;
  }
  __syncthreads();
#pragma unroll
  for (int u = 0; u < 4; ++u) {
    int crow = tr + u * 16;
    u16x4 o;
#pragma unroll
    for (int j = 0; j < 4; ++j) o[j] = f2bf(tls[crow][tc * 4 + j] * scale);
    *(u16x4*)&T[(size_t)(c0 + crow) * 1024 + r0 + tc * 4] = o;
  }
}

// ---------------- 128x128 2-phase GEMM core (proj3) ----------------
__device__ __forceinline__ void stage_tile(const unsigned short* A, const unsigned short* Bt,
                                           unsigned short* Asm, unsigned short* Bsm,
                                           int i0, int c0, int k0, int w, int srow, int scol) {
#pragma unroll
  for (int u = 0; u < 4; ++u) {
    int row = w * 32 + u * 8 + srow;
    load_lds16(&A [(size_t)(i0 + row) * 1024 + k0 + scol], &Asm[(w * 32 + u * 8) * 64]);
    load_lds16(&Bt[(size_t)(c0 + row) * 1024 + k0 + scol], &Bsm[(w * 32 + u * 8) * 64]);
  }
}

__device__ __forceinline__ void gemm_core(const unsigned short* A, const unsigned short* Bt,
                                          unsigned short* C, int ldc, int i0, int c0,
                                          unsigned short* Asm, unsigned short* Bsm) {
  const int tid = threadIdx.x, w = tid >> 6, lane = tid & 63;
  const int wr = w >> 1, wc = w & 1;
  const int srow = lane >> 3;
  const int scol = ((lane & 7) * 8) ^ (srow << 3);
  f32x4 acc[4][4] = {};

  stage_tile(A, Bt, Asm, Bsm, i0, c0, 0, w, srow, scol);

  for (int t = 0; t < 16; ++t) {
    __syncthreads();
    if (t < 15)
      stage_tile(A, Bt, Asm + ((t + 1) & 1) * 8192, Bsm + ((t + 1) & 1) * 8192,
                 i0, c0, (t + 1) * 64, w, srow, scol);
    const unsigned short* Ab = Asm + (t & 1) * 8192;
    const unsigned short* Bb = Bsm + (t & 1) * 8192;
#pragma unroll
    for (int kk = 0; kk < 2; ++kk) {
      const int colel = kk * 32 + (lane >> 4) * 8;
      short8 af[4], bf[4];
#pragma unroll
      for (int m = 0; m < 4; ++m) {
        int row = wr * 64 + m * 16 + (lane & 15);
        af[m] = *(const short8*)&Ab[row * 64 + (colel ^ ((row & 7) << 3))];
      }
#pragma unroll
      for (int n = 0; n < 4; ++n) {
        int row = wc * 64 + n * 16 + (lane & 15);
        bf[n] = *(const short8*)&Bb[row * 64 + (colel ^ ((row & 7) << 3))];
      }
#pragma unroll
      for (int m = 0; m < 4; ++m)
#pragma unroll
        for (int n = 0; n < 4; ++n)
          acc[m][n] = mfma16(af[m], bf[n], acc[m][n]);
    }
  }

#pragma unroll
  for (int m = 0; m < 4; ++m)
#pragma unroll
    for (int n = 0; n < 4; ++n) {
      const int col = c0 + wc * 64 + n * 16 + (lane & 15);
#pragma unroll
      for (int r = 0; r < 4; ++r) {
        const int row = i0 + wr * 64 + m * 16 + (lane >> 4) * 4 + r;
        C[(size_t)row * ldc + col] = f2bf(acc[m][n][r]);
      }
    }
}

__global__ __launch_bounds__(256) void proj3(const unsigned short* __restrict__ Xq, const unsigned short* __restrict__ WqT, unsigned short* __restrict__ Qb,
                                             const unsigned short* __restrict__ Xk, const unsigned short* __restrict__ WkT, unsigned short* __restrict__ Kb,
                                             const unsigned short* __restrict__ WvT, const unsigned short* __restrict__ Xv, unsigned short* __restrict__ VtB) {
  __shared__ unsigned short Asm[2 * 8192];
  __shared__ unsigned short Bsm[2 * 8192];
  int b = blockIdx.x;
  const unsigned short *A, *Bt; unsigned short* C; int ldc, i0, c0;
  if (b < 168)      { int r = b;       A = Xq;  Bt = WqT; C = Qb;  ldc = 1024; i0 = (r >> 3) * 128; c0 = (r & 7) * 128; }
  else if (b < 336) { int r = b - 168; A = Xk;  Bt = WkT; C = Kb;  ldc = 1024; i0 = (r >> 3) * 128; c0 = (r & 7) * 128; }
  else              { int r = b - 336; A = WvT; Bt = Xv;  C = VtB; ldc = NPAD; i0 = (r / 21) * 128; c0 = (r % 21) * 128; }
  gemm_core(A, Bt, C, ldc, i0, c0, Asm, Bsm);
}

// ---------------- 64x128-tile fp32-out GEMM (outproj): better machine fill ----------------
__global__ __launch_bounds__(256) void outproj(const unsigned short* __restrict__ A, const unsigned short* __restrict__ Bt,
                                               float* __restrict__ out, const float* __restrict__ bias) {
  __shared__ unsigned short Asm[2 * 4096];   // 64 x 64 x 2 bufs
  __shared__ unsigned short Bsm[2 * 8192];   // 128 x 64 x 2 bufs
  const int i0 = (blockIdx.x >> 3) * 64, c0 = (blockIdx.x & 7) * 128;
  const int tid = threadIdx.x, w = tid >> 6, lane = tid & 63;
  const int wr = w >> 1, wc = w & 1;
  const int srow = lane >> 3;
  const int scol = ((lane & 7) * 8) ^ (srow << 3);
  const int llo = lane & 15, lhi = lane >> 4;
  f32x4 acc[2][4] = {};

#define STAGE64(buf, k0)                                                                     \
  {                                                                                          \
    _Pragma("unroll")                                                                        \
    for (int u = 0; u < 2; ++u) {                                                            \
      int row = w * 16 + u * 8 + srow;                                                       \
      load_lds16(&A[(size_t)(i0 + row) * 1024 + (k0) + scol], &Asm[(buf) * 4096 + (w * 16 + u * 8) * 64]); \
    }                                                                                        \
    _Pragma("unroll")                                                                        \
    for (int u = 0; u < 4; ++u) {                                                            \
      int row = w * 32 + u * 8 + srow;                                                       \
      load_lds16(&Bt[(size_t)(c0 + row) * 1024 + (k0) + scol], &Bsm[(buf) * 8192 + (w * 32 + u * 8) * 64]); \
    }                                                                                        \
  }

  STAGE64(0, 0)
  for (int t = 0; t < 16; ++t) {
    __syncthreads();
    if (t < 15) STAGE64((t + 1) & 1, (t + 1) * 64)
    const unsigned short* Ab = Asm + (t & 1) * 4096;
    const unsigned short* Bb = Bsm + (t & 1) * 8192;
#pragma unroll
    for (int kk = 0; kk < 2; ++kk) {
      const int colel = kk * 32 + lhi * 8;
      short8 af[2], bf[4];
#pragma unroll
      for (int m = 0; m < 2; ++m) {
        int row = wr * 32 + m * 16 + llo;
        af[m] = *(const short8*)&Ab[row * 64 + (colel ^ ((row & 7) << 3))];
      }
#pragma unroll
      for (int n = 0; n < 4; ++n) {
        int row = wc * 64 + n * 16 + llo;
        bf[n] = *(const short8*)&Bb[row * 64 + (colel ^ ((row & 7) << 3))];
      }
#pragma unroll
      for (int m = 0; m < 2; ++m)
#pragma unroll
        for (int n = 0; n < 4; ++n)
          acc[m][n] = mfma16(af[m], bf[n], acc[m][n]);
    }
  }
#undef STAGE64

#pragma unroll
  for (int m = 0; m < 2; ++m)
#pragma unroll
    for (int n = 0; n < 4; ++n) {
      const int col = c0 + wc * 64 + n * 16 + llo;
      const float bb = bias[col];
#pragma unroll
      for (int r = 0; r < 4; ++r) {
        const int row = i0 + wr * 32 + m * 16 + lhi * 4 + r;
        if (row < N_SEQ) out[(size_t)row * 1024 + col] = acc[m][n][r] + bb;
      }
    }
}

// ---------------- swapped-QK MFMA flash attention (no LDS, lane-local softmax) ----------------
__global__ __launch_bounds__(256) void attn_mfma3(const unsigned short* __restrict__ Qb,
                                                  const unsigned short* __restrict__ Kb,
                                                  const unsigned short* __restrict__ Vt,
                                                  unsigned short* __restrict__ Ob,
                                                  const unsigned long long* __restrict__ mask64,
                                                  const unsigned char* __restrict__ anyN) {
  const int h = blockIdx.y;
  const int tid = threadIdx.x, w = tid >> 6, lane = tid & 63;
  const int qg = blockIdx.x * 4 + w;          // one image row of 16 queries
  const int lhi = lane >> 4, llo = lane & 15;

  // Q as B-operand (lane holds Q[q=llo][d-slice]); loop-invariant
  short8 qf0, qf1;
  {
    const size_t qrow = (size_t)(qg * 16 + llo) * 1024 + h * 64 + lhi * 8;
    qf0 = *(const short8*)&Qb[qrow];
    qf1 = *(const short8*)&Qb[qrow + 32];
  }
  const unsigned long long* mrow = &mask64[(size_t)(qg * 16 + llo) * 42];

  f32x4 acc[4] = {};                // acc[n]: D[qrow=lhi*4+r][d=n*16+llo]
  float m = -FLT_MAX, l = 0.f;      // per-lane state for q = llo (log2 domain)

  for (int jt = 0; jt < 42; ++jt) {
    int anyn = __builtin_amdgcn_readfirstlane(anyN[qg * 42 + jt]);
    if (!anyn) continue;
    const int j0 = jt * 64;
    const unsigned long long mq = mrow[jt];

    // S^T = mfma(K, Q): lane holds scores for q=llo, keys n*16 + lhi*4 + r
    float p[4][4];
#pragma unroll
    for (int n = 0; n < 4; ++n) {
      if (anyn & (1 << n)) {
        const unsigned short* kb = &Kb[(size_t)(j0 + n * 16 + llo) * 1024 + h * 64 + lhi * 8];
        short8 kf0 = *(const short8*)&kb[0];
        short8 kf1 = *(const short8*)&kb[32];
        f32x4 z = {0.f, 0.f, 0.f, 0.f};
        z = mfma16(kf0, qf0, z);
        z = mfma16(kf1, qf1, z);
#pragma unroll
        for (int r = 0; r < 4; ++r)
          p[n][r] = ((mq >> (n * 16 + lhi * 4 + r)) & 1ull) ? z[r] : -FLT_MAX;
      } else {
#pragma unroll
        for (int r = 0; r < 4; ++r) p[n][r] = -FLT_MAX;
      }
    }

    // in-lane max over 16 + 2-shfl reduce over lhi
    float tm = p[0][0];
#pragma unroll
    for (int n = 0; n < 4; ++n)
#pragma unroll
      for (int r = 0; r < 4; ++r) tm = fmaxf(tm, p[n][r]);
    tm = fmaxf(tm, __shfl_xor(tm, 16));
    tm = fmaxf(tm, __shfl_xor(tm, 32));

    const float mn = fmaxf(m, tm);
    const float f = fast_exp2(m - mn);
    float ps = 0.f;
#pragma unroll
    for (int n = 0; n < 4; ++n)
#pragma unroll
      for (int r = 0; r < 4; ++r) {
        float pv = fast_exp2(p[n][r] - mn);
        p[n][r] = pv;
        ps += pv;
      }
    ps += __shfl_xor(ps, 16);
    ps += __shfl_xor(ps, 32);
    l = l * f + ps;
    m = mn;

    // broadcast rescale factor into acc row-layout (q-row = lhi*4 + r lives at lane llo')
    float fr[4];
#pragma unroll
    for (int r = 0; r < 4; ++r) fr[r] = __shfl(f, lhi * 4 + r);
#pragma unroll
    for (int n = 0; n < 4; ++n)
#pragma unroll
      for (int r = 0; r < 4; ++r) acc[n][r] *= fr[r];

    // PV with pi-permuted k-order: lane supplies its own 8 P values per 32-key half
#pragma unroll
    for (int kk = 0; kk < 2; ++kk) {
      if (!(anyn & (kk ? 12 : 3))) continue;
      const int n0 = kk * 2;
      u32x4 pw;
      pw[0] = cvt_pk_bf16(p[n0][0], p[n0][1]);
      pw[1] = cvt_pk_bf16(p[n0][2], p[n0][3]);
      pw[2] = cvt_pk_bf16(p[n0 + 1][0], p[n0 + 1][1]);
      pw[3] = cvt_pk_bf16(p[n0 + 1][2], p[n0 + 1][3]);
      short8 pf = __builtin_bit_cast(short8, pw);
#pragma unroll
      for (int n = 0; n < 4; ++n) {
        const unsigned short* vb = &Vt[(size_t)(h * 64 + n * 16 + llo) * NPAD + j0 + kk * 32 + lhi * 4];
        s16x4 v0 = *(const s16x4*)&vb[0];
        s16x4 v1 = *(const s16x4*)&vb[16];
        short8 vf;
        vf[0] = v0[0]; vf[1] = v0[1]; vf[2] = v0[2]; vf[3] = v0[3];
        vf[4] = v1[0]; vf[5] = v1[1]; vf[6] = v1[2]; vf[7] = v1[3];
        acc[n] = mfma16(pf, vf, acc[n]);
      }
    }
  }

  // epilogue: fetch 1/l for acc's rows, write
  float li[4];
#pragma unroll
  for (int r = 0; r < 4; ++r) li[r] = 1.0f / __shfl(l, lhi * 4 + r);
#pragma unroll
  for (int r = 0; r < 4; ++r) {
    const int row = qg * 16 + lhi * 4 + r;
    if (row < N_SEQ) {
#pragma unroll
      for (int n = 0; n < 4; ++n)
        Ob[(size_t)row * 1024 + h * 64 + n * 16 + llo] = f2bf(acc[n][r] * li[r]);
    }
  }
}

// ---------------- row 2560: uniform attention = mean over all 2561 V rows ----------------
__global__ void fix_row2560(const unsigned short* __restrict__ Vt, unsigned short* __restrict__ Ob) {
  const int d = blockIdx.x, lane = threadIdx.x;
  float s = 0.f;
  for (int j = lane; j < N_SEQ; j += 64) s += bf2f(Vt[(size_t)d * NPAD + j]);
  s += __shfl_xor(s, 1);  s += __shfl_xor(s, 2);  s += __shfl_xor(s, 4);
  s += __shfl_xor(s, 8);  s += __shfl_xor(s, 16); s += __shfl_xor(s, 32);
  if (lane == 0) Ob[(size_t)2560 * 1024 + d] = f2bf(s * (1.0f / 2561.0f));
}

extern "C" void kernel_launch(void* const* d_in, const int* in_sizes, int n_in,
                              void* d_out, int out_size, void* d_ws, size_t ws_size,
                              hipStream_t stream) {
  const float* q  = (const float*)d_in[0];
  const float* k  = (const float*)d_in[1];
  const float* v  = (const float*)d_in[2];
  const float* Wq = (const float*)d_in[3];
  const float* Wk = (const float*)d_in[4];
  const float* Wv = (const float*)d_in[5];
  const float* Wo = (const float*)d_in[6];
  const float* bo = (const float*)d_in[7];

  unsigned short* ws = (unsigned short*)d_ws;
  const size_t MW = (size_t)1024 * 1024;
  unsigned short* Xq  = ws;
  unsigned short* Xk  = ws + SEG;
  unsigned short* Xv  = ws + 2 * SEG;
  unsigned short* Qb  = ws + 3 * SEG;
  unsigned short* Kb  = ws + 4 * SEG;
  unsigned short* VtB = ws + 5 * SEG;
  unsigned short* WqT = ws + 6 * SEG;
  unsigned short* WkT = WqT + MW;
  unsigned short* WvT = WqT + 2 * MW;
  unsigned short* WoT = WqT + 3 * MW;
  unsigned long long* mask64 = (unsigned long long*)(WqT + 4 * MW);
  unsigned char* anyN = (unsigned char*)(mask64 + 2688 * 42);
  unsigned short* ObB = Xq;            // reuse Xq after projections

  setup_mask<<<441, 256, 0, stream>>>(mask64);
  setup_any<<<28, 256, 0, stream>>>(mask64, anyN);
  cvt_x3<<<dim3(1344, 3), 256, 0, stream>>>(q, k, v, Xq, Xk, Xv);
  cvt_wT<<<dim3(16, 16, 4), 256, 0, stream>>>(Wq, Wk, Wv, Wo, WqT, WkT, WvT, WoT);

  proj3<<<504, 256, 0, stream>>>(Xq, WqT, Qb, Xk, WkT, Kb, WvT, Xv, VtB);

  attn_mfma3<<<dim3(42, 16), 256, 0, stream>>>(Qb, Kb, VtB, ObB, mask64, anyN);
  fix_row2560<<<1024, 64, 0, stream>>>(VtB, ObB);

  outproj<<<336, 256, 0, stream>>>(ObB, WoT, (float*)d_out, bo);
}